// Round 9
// baseline (104.793 us; speedup 1.0000x reference)
//
#include <hip/hip_runtime.h>
#include <math.h>

#define NUM_T   1000
#define NUM_R   8
#define NBINS   200
#define FPB     2                       // frames per block -> grid 8*500=4000
#define TTSZ    224                     // padded threshold table (inf tail)
#define TYSTR   217                     // u32 rows per type: 200 bins + 17 dump
#define NCOL    4                       // histogram columns (tid&3)
#define HWORDS  (3*TYSTR*NCOL)          // 2604 u32 words

__device__ __forceinline__ float approx_sqrt(float x) {
    float r; asm("v_sqrt_f32 %0, %1" : "=v"(r) : "v"(x)); return r;
}
__device__ __forceinline__ float fract_(float x) {
#if __has_builtin(__builtin_amdgcn_fractf)
    return __builtin_amdgcn_fractf(x);
#else
    return x - floorf(x);
#endif
}
// broadcast lane `sidx`'s copy of v to all lanes (VALU readlane, NOT ds_bpermute)
__device__ __forceinline__ float rlanef(float v, int sidx) {
    return __uint_as_float(__builtin_amdgcn_readlane(__float_as_uint(v), sidx));
}

// ---------------------------------------------------------------------------
// Bit-exact binning on squared distances (validated R1-R7, absmax 3.906e-3):
//   TT[k] = min{s : sqrtf(s) >= bins[k]}; TT[200] = Tp (d<=10 edge).
//   Fast path k=(int)z, z=v_sqrt(400s), exact unless frac(z) within +-2e-4
//   of an integer (boundary-image analysis R3). Ambiguous -> whole-wave-vote
//   slow path: k += (s>=TT[k+1]) - (s<TT[k]) (no-op for exact lanes);
//   k<0 (s<TT[0], incl. d==0 -- always ambiguous since z<3e-5) -> k=216.
//   No explicit range test: d>10 lands at k=200..215; k=200..216 are
//   PER-TYPE dump rows (TYSTR=217 stride), never flushed.
// Histogram (R8): u32 counters, 4 columns. word = (type*217 + k)*4 + (tid&3).
//   Bank = (col + 4k) mod 32: the 4 columns own disjoint bank sets of 8;
//   each column's 16 lanes spread over its 8 banks by k. One v_lshl_add for
//   the address, constant add value (no u16 packing VALU).
// DS-read elimination (R8): for HH-cross and HO the j-position is
//   wave-uniform and lane j already holds it in registers (pi1/piO), so
//   pj = readlane(reg, j) -- 3 VALU broadcasts replace one b128 DS read.
//   Rotations keep per-lane ds_reads (per-lane j).
// Pair enumeration (symmetric types once, weight 2) as R4-R7.
// ---------------------------------------------------------------------------
__global__ __launch_bounds__(256) void rdf_hist_kernel(
    const float* __restrict__ radii,      // [T][R][192][3]
    const float* __restrict__ lat,        // [3]
    unsigned int* __restrict__ gh)        // [R][3][200]
{
    #pragma clang fp contract(off)
    __shared__ float4 posOx[96], posH0[96], posH1[96];
    __shared__ float TT[TTSZ];
    __shared__ __align__(16) unsigned int hist[HWORDS];

    const int tid = threadIdx.x;

    if (tid < TTSZ) {
        float v;
        if (tid <= 200) {
            float b;
            if (tid < NBINS) {
                const double step = (10.0 - 1e-6) / 200.0;
                b = (float)(1e-6 + (double)tid * step);
            } else {
                b = __uint_as_float(__float_as_uint(10.0f) + 1u); // nextafter(10,inf)
            }
            unsigned lo = 0u, hi = 0x7F800000u;
            while (lo < hi) {
                unsigned mid = (lo + hi) >> 1;
                if (sqrtf(__uint_as_float(mid)) >= b) hi = mid; else lo = mid + 1;
            }
            v = __uint_as_float(lo);
        } else {
            v = __uint_as_float(0x7F800000u);   // +inf padding
        }
        TT[tid] = v;
    }
    for (int i = tid; i < HWORDS; i += 256) hist[i] = 0u;

    const float Lx = lat[0], Ly = lat[1], Lz = lat[2];
    __syncthreads();

    const int col = tid & (NCOL - 1);

// shared tail of the pair body: from (tx,ty,tz) to the atomic.
#define PTAIL(TB, W)                                                         \
    {                                                                        \
        float ax = fminf(fabsf(tx), Lx - fabsf(tx));                         \
        float ay = fminf(fabsf(ty), Ly - fabsf(ty));                         \
        float az = fminf(fabsf(tz), Lz - fabsf(tz));                         \
        float s  = (ax*ax + ay*ay) + az*az;                                  \
        float z  = approx_sqrt(s * 400.0f);                                  \
        int   k  = (int)z;                                                   \
        float m  = fract_(z);                                                \
        bool amb = fabsf(m - 0.5f) > 0.49980f;                               \
        if (__builtin_expect(__any(amb), 0)) {                               \
            float tlo = TT[k], thi = TT[k + 1];                              \
            k += ((s >= thi) ? 1 : 0) - ((s < tlo) ? 1 : 0);                 \
            if (k < 0) k = 216;                                              \
        }                                                                    \
        atomicAdd(&hist[(TB) + (k << 2)], (W));                              \
    }

#define PAIRV(PI, PJ, TB, W)                                                 \
    {                                                                        \
        float tx = (PI).x - (PJ).x;                                          \
        float ty = (PI).y - (PJ).y;                                          \
        float tz = (PI).z - (PJ).z;                                          \
        PTAIL(TB, W)                                                         \
    }
#define PAIRS(PI, SX, SY, SZ, TB, W)                                         \
    {                                                                        \
        float tx = (PI).x - (SX);                                            \
        float ty = (PI).y - (SY);                                            \
        float tz = (PI).z - (SZ);                                            \
        PTAIL(TB, W)                                                         \
    }

    const int rep   = blockIdx.x & (NUM_R - 1);
    const int chunk = blockIdx.x / NUM_R;
    const int l     = tid & 63;
    const int q     = tid >> 6;                    // wave id 0..3 (uniform)
    const int qu    = __builtin_amdgcn_readfirstlane(q);
    const int tbOO  = col;                         // type 0 rows
    const int tbHH  = col + (TYSTR << 2);          // type 1 rows
    const int tbHO  = col + (2 * TYSTR << 2);      // type 2 rows

    // prefetch frame 0 raw coords
    float rvx = 0.f, rvy = 0.f, rvz = 0.f;
    {
        const float* s0 = radii + ((size_t)(chunk * FPB) * NUM_R + rep) * (192 * 3);
        if (tid < 192) { rvx = s0[tid*3+0]; rvy = s0[tid*3+1]; rvz = s0[tid*3+2]; }
    }

    #pragma unroll 1
    for (int f = 0; f < FPB; ++f) {
        __syncthreads();
        if (tid < 192) {
            float ux = rvx / Lx; ux -= floorf(ux);
            float uy = rvy / Ly; uy -= floorf(uy);
            float uz = rvz / Lz; uz -= floorf(uz);
            float4 p = make_float4(ux*Lx, uy*Ly, uz*Lz, 0.0f);
            if (tid < 64)       { posOx[tid] = p;  if (tid < 32) posOx[tid+64] = p; }
            else if (tid < 128) { int h = tid-64;  posH0[h] = p; if (h < 32) posH0[h+64] = p; }
            else                { int h = tid-128; posH1[h] = p; if (h < 32) posH1[h+64] = p; }
        }
        __syncthreads();

        if (f + 1 < FPB && tid < 192) {   // prefetch next frame during compute
            const float* s1 = radii + ((size_t)(chunk * FPB + f + 1) * NUM_R + rep) * (192 * 3);
            rvx = s1[tid*3+0]; rvy = s1[tid*3+1]; rvz = s1[tid*3+2];
        }

        const float4 piO = posOx[l];
        const float4 pi0 = posH0[l];
        const float4 pi1 = posH1[l];
        const int jb = l + q + 1;

        // ---- O-O rotation: k = q+1+4*it; k=32 (q=3,it=7) half-covered ----
        #pragma unroll
        for (int it = 0; it < 7; ++it) { float4 pj = posOx[jb + 4*it]; PAIRV(piO, pj, tbOO, 2u); }
        if (q < 3 || l < 32)           { float4 pj = posOx[jb + 28];   PAIRV(piO, pj, tbOO, 2u); }

        // ---- H0 diag rotation ----
        #pragma unroll
        for (int it = 0; it < 7; ++it) { float4 pj = posH0[jb + 4*it]; PAIRV(pi0, pj, tbHH, 2u); }
        if (q < 3 || l < 32)           { float4 pj = posH0[jb + 28];   PAIRV(pi0, pj, tbHH, 2u); }

        // ---- H1 diag rotation ----
        #pragma unroll
        for (int it = 0; it < 7; ++it) { float4 pj = posH1[jb + 4*it]; PAIRV(pi1, pj, tbHH, 2u); }
        if (q < 3 || l < 32)           { float4 pj = posH1[jb + 28];   PAIRV(pi1, pj, tbHH, 2u); }

        // ---- HH cross (H0 x H1), weight 2: pj via readlane broadcast ----
        #pragma unroll 4
        for (int jj = 0; jj < 16; ++jj) {
            const int idx = qu * 16 + jj;
            float sx = rlanef(pi1.x, idx), sy = rlanef(pi1.y, idx), sz = rlanef(pi1.z, idx);
            PAIRS(pi0, sx, sy, sz, tbHH, 2u);
        }
        // ---- H-O ordered, weight 1: one readlane O feeds both H rows ----
        #pragma unroll 4
        for (int jj = 0; jj < 16; ++jj) {
            const int idx = qu * 16 + jj;
            float sx = rlanef(piO.x, idx), sy = rlanef(piO.y, idx), sz = rlanef(piO.z, idx);
            PAIRS(pi0, sx, sy, sz, tbHO, 1u);
            PAIRS(pi1, sx, sy, sz, tbHO, 1u);
        }
    }
#undef PAIRV
#undef PAIRS
#undef PTAIL

    __syncthreads();
    // flush logical rows (type p, bin b): one b128 read of the 4 columns.
    for (int idx = tid; idx < 3 * NBINS; idx += 256) {
        const int p = idx / 200;
        const int b = idx - p * 200;
        const uint4 v = *reinterpret_cast<const uint4*>(&hist[(p * TYSTR + b) << 2]);
        unsigned sum = (v.x + v.y) + (v.z + v.w);
        if (sum) atomicAdd(&gh[rep * 3 * NBINS + idx], sum);
    }
}

// ---------------------------------------------------------------------------
__global__ __launch_bounds__(256) void rdf_final_kernel(
    const unsigned int* __restrict__ gh,  // [R][3][200]
    const float* __restrict__ gt,         // [3][200]
    const float* __restrict__ lat,        // [3]
    float* __restrict__ out)              // [R][600] then [R] maxmae
{
    #pragma clang fp contract(off)
    const int rep = blockIdx.x;
    const int tid = threadIdx.x;
    __shared__ float bins[NBINS + 1];
    __shared__ float red[256];

    for (int i = tid; i <= NBINS; i += 256) {
        const double step = (10.0 - 1e-6) / 200.0;
        bins[i] = (i == NBINS) ? 10.0f : (float)(1e-6 + (double)i * step);
    }
    __syncthreads();

    const float vol = (lat[0] * lat[1]) * lat[2];
    const float C   = 4.18879020478639053f;   // float(4/3*pi)
    const int npairs[3] = { NUM_T*64*64, NUM_T*128*128, NUM_T*128*64 };

    float maxmae = -3.0e38f;
    for (int p = 0; p < 3; ++p) {
        float diff = 0.0f;
        if (tid < NBINS) {
            float b0 = bins[tid], b1 = bins[tid + 1];
            float shell = C * (b1*b1*b1 - b0*b0*b0);
            float rho = (float)npairs[p] / vol;
            float g = (float)gh[(rep*3 + p)*NBINS + tid] / (rho * shell);
            out[rep*3*NBINS + p*NBINS + tid] = g;
            diff = fabsf(g - gt[p*NBINS + tid]);
        }
        red[tid] = diff;
        __syncthreads();
        for (int s = 128; s > 0; s >>= 1) {
            if (tid < s) red[tid] += red[tid + s];
            __syncthreads();
        }
        if (tid == 0) {
            float mae = 10.0f * (red[0] / 200.0f);
            if (mae > maxmae) maxmae = mae;
        }
        __syncthreads();
    }
    if (tid == 0) out[NUM_R*3*NBINS + rep] = maxmae;
}

// ---------------------------------------------------------------------------
extern "C" void kernel_launch(void* const* d_in, const int* in_sizes, int n_in,
                              void* d_out, int out_size, void* d_ws, size_t ws_size,
                              hipStream_t stream) {
    const float* radii = (const float*)d_in[0];
    const float* lat   = (const float*)d_in[1];
    const float* gt    = (const float*)d_in[2];
    unsigned int* gh   = (unsigned int*)d_ws;

    hipMemsetAsync(gh, 0, NUM_R * 3 * NBINS * sizeof(unsigned int), stream);

    dim3 grid(NUM_R * (NUM_T / FPB));     // 8 * 500 = 4000 blocks
    hipLaunchKernelGGL(rdf_hist_kernel, grid, dim3(256), 0, stream,
                       radii, lat, gh);
    hipLaunchKernelGGL(rdf_final_kernel, dim3(NUM_R), dim3(256), 0, stream,
                       gh, gt, lat, (float*)d_out);
}

// Round 10
// 93.570 us; speedup vs baseline: 1.1199x; 1.1199x over previous
//
#include <hip/hip_runtime.h>
#include <math.h>

#define NUM_T   1000
#define NUM_R   8
#define NBINS   200
#define FPB     2                       // frames per block -> grid 8*500=4000
#define TTSZ    224                     // padded threshold table (inf tail)
#define TYSTR   217                     // u32 rows per type: 200 bins + 17 dump
#define NCOL    4                       // histogram columns (tid&3)
#define HWORDS  (3*TYSTR*NCOL)          // 2604 u32 words

__device__ __forceinline__ float approx_sqrt(float x) {
    float r; asm("v_sqrt_f32 %0, %1" : "=v"(r) : "v"(x)); return r;
}
__device__ __forceinline__ float fract_(float x) {
#if __has_builtin(__builtin_amdgcn_fractf)
    return __builtin_amdgcn_fractf(x);
#else
    return x - floorf(x);
#endif
}

// ---------------------------------------------------------------------------
// Bit-exact binning on squared distances (validated R1-R8, absmax 3.906e-3):
//   TT[k] = min{s : sqrtf(s) >= bins[k]}; TT[200] = Tp (d<=10 edge).
//   Fast path k=(int)z, z=v_sqrt(400s), exact unless frac(z) within +-2e-4
//   of an integer (boundary-image analysis R3). Ambiguous -> whole-wave-vote
//   slow path: k += (s>=TT[k+1]) - (s<TT[k]) (no-op for exact lanes);
//   k<0 (s<TT[0], incl. d==0) -> k=216. No explicit range test: d>10 lands
//   in PER-TYPE dump rows k=200..216 (TYSTR=217), never flushed.
// Histogram: u32 counters, 4 columns. word = (type*217 + k)*4 + (tid&3).
//   4 columns own disjoint bank sets of 8; lanes spread by k. (R8 layout.)
// R9: ILP restructure. R4-R8 were all flat because VGPR_Count=20 forced a
//   serialized dependent chain per pair (ds_read latency ~60-120cy exposed
//   every pair, ~5.5 waves/SIMD can't hide it). Now: batch 8 independent
//   ds_read_b128 into a register array, one lgkmcnt wait, then 8 bodies.
//   __launch_bounds__(256,8) keeps VGPR<=64 (8 blocks/CU occupancy).
//   HH-cross/HO revert to (batched) uniform LDS reads: R8 showed readlane
//   VALU broadcasts are worse than DS broadcast reads.
// Pair enumeration (symmetric types once, weight 2) as R4-R8.
// ---------------------------------------------------------------------------
__global__ __launch_bounds__(256, 8) void rdf_hist_kernel(
    const float* __restrict__ radii,      // [T][R][192][3]
    const float* __restrict__ lat,        // [3]
    unsigned int* __restrict__ gh)        // [R][3][200]
{
    #pragma clang fp contract(off)
    __shared__ float4 posOx[96], posH0[96], posH1[96];
    __shared__ float TT[TTSZ];
    __shared__ __align__(16) unsigned int hist[HWORDS];

    const int tid = threadIdx.x;

    if (tid < TTSZ) {
        float v;
        if (tid <= 200) {
            float b;
            if (tid < NBINS) {
                const double step = (10.0 - 1e-6) / 200.0;
                b = (float)(1e-6 + (double)tid * step);
            } else {
                b = __uint_as_float(__float_as_uint(10.0f) + 1u); // nextafter(10,inf)
            }
            unsigned lo = 0u, hi = 0x7F800000u;
            while (lo < hi) {
                unsigned mid = (lo + hi) >> 1;
                if (sqrtf(__uint_as_float(mid)) >= b) hi = mid; else lo = mid + 1;
            }
            v = __uint_as_float(lo);
        } else {
            v = __uint_as_float(0x7F800000u);   // +inf padding
        }
        TT[tid] = v;
    }
    for (int i = tid; i < HWORDS; i += 256) hist[i] = 0u;

    const float Lx = lat[0], Ly = lat[1], Lz = lat[2];
    __syncthreads();

    const int col = tid & (NCOL - 1);

#define PAIRV(PI, PJ, TB, W)                                                 \
    {                                                                        \
        float tx = (PI).x - (PJ).x;                                          \
        float ty = (PI).y - (PJ).y;                                          \
        float tz = (PI).z - (PJ).z;                                          \
        float ax = fminf(fabsf(tx), Lx - fabsf(tx));                         \
        float ay = fminf(fabsf(ty), Ly - fabsf(ty));                         \
        float az = fminf(fabsf(tz), Lz - fabsf(tz));                         \
        float s  = (ax*ax + ay*ay) + az*az;                                  \
        float z  = approx_sqrt(s * 400.0f);                                  \
        int   k  = (int)z;                                                   \
        float m  = fract_(z);                                                \
        bool amb = fabsf(m - 0.5f) > 0.49980f;                               \
        if (__builtin_expect(__any(amb), 0)) {                               \
            float tlo = TT[k], thi = TT[k + 1];                              \
            k += ((s >= thi) ? 1 : 0) - ((s < tlo) ? 1 : 0);                 \
            if (k < 0) k = 216;                                              \
        }                                                                    \
        atomicAdd(&hist[(TB) + (k << 2)], (W));                              \
    }

    const int rep   = blockIdx.x & (NUM_R - 1);
    const int chunk = blockIdx.x / NUM_R;
    const int l     = tid & 63;
    const int q     = tid >> 6;                    // wave id 0..3 (uniform)
    const int tbOO  = col;                         // type 0 rows
    const int tbHH  = col + (TYSTR << 2);          // type 1 rows
    const int tbHO  = col + (2 * TYSTR << 2);      // type 2 rows

    // prefetch frame 0 raw coords
    float rvx = 0.f, rvy = 0.f, rvz = 0.f;
    {
        const float* s0 = radii + ((size_t)(chunk * FPB) * NUM_R + rep) * (192 * 3);
        if (tid < 192) { rvx = s0[tid*3+0]; rvy = s0[tid*3+1]; rvz = s0[tid*3+2]; }
    }

    #pragma unroll 1
    for (int f = 0; f < FPB; ++f) {
        __syncthreads();
        if (tid < 192) {
            float ux = rvx / Lx; ux -= floorf(ux);
            float uy = rvy / Ly; uy -= floorf(uy);
            float uz = rvz / Lz; uz -= floorf(uz);
            float4 p = make_float4(ux*Lx, uy*Ly, uz*Lz, 0.0f);
            if (tid < 64)       { posOx[tid] = p;  if (tid < 32) posOx[tid+64] = p; }
            else if (tid < 128) { int h = tid-64;  posH0[h] = p; if (h < 32) posH0[h+64] = p; }
            else                { int h = tid-128; posH1[h] = p; if (h < 32) posH1[h+64] = p; }
        }
        __syncthreads();

        if (f + 1 < FPB && tid < 192) {   // prefetch next frame during compute
            const float* s1 = radii + ((size_t)(chunk * FPB + f + 1) * NUM_R + rep) * (192 * 3);
            rvx = s1[tid*3+0]; rvy = s1[tid*3+1]; rvz = s1[tid*3+2];
        }

        const float4 piO = posOx[l];
        const float4 pi0 = posH0[l];
        const float4 pi1 = posH1[l];
        const int jb = l + q + 1;

        // ---- O-O rotation: batch 8 loads, then 8 bodies (last guarded) ----
        {
            float4 pjs[8];
            #pragma unroll
            for (int it = 0; it < 8; ++it) pjs[it] = posOx[jb + 4*it];
            #pragma unroll
            for (int it = 0; it < 7; ++it) PAIRV(piO, pjs[it], tbOO, 2u)
            if (q < 3 || l < 32) PAIRV(piO, pjs[7], tbOO, 2u)
        }
        // ---- H0 diag rotation ----
        {
            float4 pjs[8];
            #pragma unroll
            for (int it = 0; it < 8; ++it) pjs[it] = posH0[jb + 4*it];
            #pragma unroll
            for (int it = 0; it < 7; ++it) PAIRV(pi0, pjs[it], tbHH, 2u)
            if (q < 3 || l < 32) PAIRV(pi0, pjs[7], tbHH, 2u)
        }
        // ---- H1 diag rotation ----
        {
            float4 pjs[8];
            #pragma unroll
            for (int it = 0; it < 8; ++it) pjs[it] = posH1[jb + 4*it];
            #pragma unroll
            for (int it = 0; it < 7; ++it) PAIRV(pi1, pjs[it], tbHH, 2u)
            if (q < 3 || l < 32) PAIRV(pi1, pjs[7], tbHH, 2u)
        }
        // ---- HH cross (H0 x H1), weight 2: batched uniform reads ----
        #pragma unroll 1
        for (int b2 = 0; b2 < 2; ++b2) {
            float4 pjc[8];
            #pragma unroll
            for (int jj = 0; jj < 8; ++jj) pjc[jj] = posH1[q*16 + b2*8 + jj];
            #pragma unroll
            for (int jj = 0; jj < 8; ++jj) PAIRV(pi0, pjc[jj], tbHH, 2u)
        }
        // ---- H-O ordered, weight 1: each uniform O feeds both H rows ----
        #pragma unroll 1
        for (int b2 = 0; b2 < 2; ++b2) {
            float4 pjc[8];
            #pragma unroll
            for (int jj = 0; jj < 8; ++jj) pjc[jj] = posOx[q*16 + b2*8 + jj];
            #pragma unroll
            for (int jj = 0; jj < 8; ++jj) {
                PAIRV(pi0, pjc[jj], tbHO, 1u)
                PAIRV(pi1, pjc[jj], tbHO, 1u)
            }
        }
    }
#undef PAIRV

    __syncthreads();
    // flush logical rows (type p, bin b): one b128 read of the 4 columns.
    for (int idx = tid; idx < 3 * NBINS; idx += 256) {
        const int p = idx / 200;
        const int b = idx - p * 200;
        const uint4 v = *reinterpret_cast<const uint4*>(&hist[(p * TYSTR + b) << 2]);
        unsigned sum = (v.x + v.y) + (v.z + v.w);
        if (sum) atomicAdd(&gh[rep * 3 * NBINS + idx], sum);
    }
}

// ---------------------------------------------------------------------------
__global__ __launch_bounds__(256) void rdf_final_kernel(
    const unsigned int* __restrict__ gh,  // [R][3][200]
    const float* __restrict__ gt,         // [3][200]
    const float* __restrict__ lat,        // [3]
    float* __restrict__ out)              // [R][600] then [R] maxmae
{
    #pragma clang fp contract(off)
    const int rep = blockIdx.x;
    const int tid = threadIdx.x;
    __shared__ float bins[NBINS + 1];
    __shared__ float red[256];

    for (int i = tid; i <= NBINS; i += 256) {
        const double step = (10.0 - 1e-6) / 200.0;
        bins[i] = (i == NBINS) ? 10.0f : (float)(1e-6 + (double)i * step);
    }
    __syncthreads();

    const float vol = (lat[0] * lat[1]) * lat[2];
    const float C   = 4.18879020478639053f;   // float(4/3*pi)
    const int npairs[3] = { NUM_T*64*64, NUM_T*128*128, NUM_T*128*64 };

    float maxmae = -3.0e38f;
    for (int p = 0; p < 3; ++p) {
        float diff = 0.0f;
        if (tid < NBINS) {
            float b0 = bins[tid], b1 = bins[tid + 1];
            float shell = C * (b1*b1*b1 - b0*b0*b0);
            float rho = (float)npairs[p] / vol;
            float g = (float)gh[(rep*3 + p)*NBINS + tid] / (rho * shell);
            out[rep*3*NBINS + p*NBINS + tid] = g;
            diff = fabsf(g - gt[p*NBINS + tid]);
        }
        red[tid] = diff;
        __syncthreads();
        for (int s = 128; s > 0; s >>= 1) {
            if (tid < s) red[tid] += red[tid + s];
            __syncthreads();
        }
        if (tid == 0) {
            float mae = 10.0f * (red[0] / 200.0f);
            if (mae > maxmae) maxmae = mae;
        }
        __syncthreads();
    }
    if (tid == 0) out[NUM_R*3*NBINS + rep] = maxmae;
}

// ---------------------------------------------------------------------------
extern "C" void kernel_launch(void* const* d_in, const int* in_sizes, int n_in,
                              void* d_out, int out_size, void* d_ws, size_t ws_size,
                              hipStream_t stream) {
    const float* radii = (const float*)d_in[0];
    const float* lat   = (const float*)d_in[1];
    const float* gt    = (const float*)d_in[2];
    unsigned int* gh   = (unsigned int*)d_ws;

    hipMemsetAsync(gh, 0, NUM_R * 3 * NBINS * sizeof(unsigned int), stream);

    dim3 grid(NUM_R * (NUM_T / FPB));     // 8 * 500 = 4000 blocks
    hipLaunchKernelGGL(rdf_hist_kernel, grid, dim3(256), 0, stream,
                       radii, lat, gh);
    hipLaunchKernelGGL(rdf_final_kernel, dim3(NUM_R), dim3(256), 0, stream,
                       gh, gt, lat, (float*)d_out);
}